// Round 4
// baseline (513.130 us; speedup 1.0000x reference)
//
#include <hip/hip_runtime.h>
#include <hip/hip_bf16.h>
#include <stdint.h>

using bf16x8 = __attribute__((ext_vector_type(8))) __bf16;
using bf16x4 = __attribute__((ext_vector_type(4))) __bf16;
using f32x4  = __attribute__((ext_vector_type(4))) float;

typedef const uint32_t __attribute__((address_space(1)))* gas_ptr;
typedef uint32_t __attribute__((address_space(3)))* las_ptr;

__device__ __forceinline__ void load_lds16(const void* g, void* l) {
    __builtin_amdgcn_global_load_lds((gas_ptr)g, (las_ptr)l, 16, 0, 0);
}

// cprelu post-normalization constants (PRELU_INIT = 0.25)
#define PM  0.29920671030107454f
#define PIS 1.5046096f
#define RHALF 0.70710678118654752f

// ---------------------------------------------------------------- k_prep
__global__ __launch_bounds__(256) void k_prep(const float* __restrict__ w1,
                                              const float* __restrict__ w2,
                                              const float* __restrict__ wm,
                                              const float* __restrict__ wsw,
                                              __bf16* __restrict__ W1p,
                                              __bf16* __restrict__ W2p,
                                              __bf16* __restrict__ WMp,
                                              __bf16* __restrict__ WSp)
{
    const int id = blockIdx.x * 256 + threadIdx.x;
    const int stride = gridDim.x * 256;
    for (int i = id; i < 96 * 64; i += stride) {
        int oc = i >> 6, ic = i & 63;
        W1p[i] = (__bf16)((oc < 83) ? w1[oc * 64 + ic] : 0.f);
    }
    for (int i = id; i < 112 * 96; i += stride) {
        int oc = i / 96, ic = i % 96;
        W2p[i] = (__bf16)((oc < 102 && ic < 83) ? w2[oc * 83 + ic] : 0.f);
    }
    for (int i = id; i < 128 * 128; i += stride) {
        int oc = i >> 7, ic = i & 127;
        WMp[i] = (__bf16)((ic < 102) ? wm[oc * 102 + ic] : 0.f);
    }
    for (int i = id; i < 128 * 64; i += stride) {
        WSp[i] = (__bf16)wsw[i];
    }
}

// ---------------------------------------------------------------- k_conv
// Fused: conn fp32 -> bf16 (row-private, read-all-then-write so in-place is
// safe) + per-row max + tie-index collection (exact fp32 equality, cap 16).
// Standalone (tiny LDS) so the memory-bound stream runs at high occupancy.
__global__ __launch_bounds__(256) void k_conv(const float* __restrict__ conn,
                                              __bf16* __restrict__ cb,
                                              size_t rowstride,
                                              int* __restrict__ cnt,
                                              int* __restrict__ idx)
{
    const int o = blockIdx.x;
    const int t = threadIdx.x;
    const float* row = conn + (size_t)o * 8192;
    float4 v[8];
    float m = -1e30f;
#pragma unroll
    for (int q = 0; q < 8; q++) {
        v[q] = *(const float4*)(row + (size_t)(q * 256 + t) * 4);
        m = fmaxf(m, fmaxf(fmaxf(v[q].x, v[q].y), fmaxf(v[q].z, v[q].w)));
    }
    __syncthreads();   // all reads drained before in-place overwrite
    __bf16* drow = cb + (size_t)o * rowstride;
#pragma unroll
    for (int q = 0; q < 8; q++) {
        bf16x4 w;
        w[0] = (__bf16)v[q].x; w[1] = (__bf16)v[q].y;
        w[2] = (__bf16)v[q].z; w[3] = (__bf16)v[q].w;
        *(bf16x4*)(drow + (size_t)(q * 256 + t) * 4) = w;
    }
#pragma unroll
    for (int off = 32; off > 0; off >>= 1) m = fmaxf(m, __shfl_down(m, off, 64));
    __shared__ float wmax[4];
    __shared__ int scnt;
    if ((t & 63) == 0) wmax[t >> 6] = m;
    if (t == 0) scnt = 0;
    __syncthreads();
    const float rmax = fmaxf(fmaxf(wmax[0], wmax[1]), fmaxf(wmax[2], wmax[3]));
#pragma unroll
    for (int q = 0; q < 8; q++) {
        float vv[4] = {v[q].x, v[q].y, v[q].z, v[q].w};
#pragma unroll
        for (int e = 0; e < 4; e++) {
            if (vv[e] >= rmax) {
                int p = atomicAdd(&scnt, 1);
                if (p < 16) idx[o * 16 + p] = (q * 256 + t) * 4 + e;
            }
        }
    }
    __syncthreads();
    if (t == 0) cnt[o] = scnt < 16 ? scnt : 16;
}

// ---------------------------------------------------------------- k_chain
template<int KS>
__device__ __forceinline__ f32x4 mfma_tile(const __bf16* __restrict__ W, int wstride, int mt,
                                           const __bf16* B, int bstride, int nt, int lane)
{
    f32x4 acc = {0.f, 0.f, 0.f, 0.f};
    const int l15 = lane & 15;
    const int kg  = (lane >> 4) << 3;
    const __bf16* wp = W + (mt * 16 + l15) * wstride + kg;
    const __bf16* bp = B + (nt * 16 + l15) * bstride + kg;
#pragma unroll
    for (int ks = 0; ks < KS; ks++) {
        bf16x8 av = *(const bf16x8*)(wp + ks * 32);
        bf16x8 bv = *(const bf16x8*)(bp + ks * 32);
        acc = __builtin_amdgcn_mfma_f32_16x16x32_bf16(av, bv, acc, 0, 0, 0);
    }
    return acc;
}

__global__ __launch_bounds__(256) void k_chain(
    const float* __restrict__ x,
    const float* __restrict__ b1, const float* __restrict__ p1,
    const float* __restrict__ b2, const float* __restrict__ p2,
    const float* __restrict__ bm, const float* __restrict__ bs,
    const __bf16* __restrict__ W1p, const __bf16* __restrict__ W2p,
    const __bf16* __restrict__ WMp, const __bf16* __restrict__ WSp,
    __bf16* __restrict__ h3, __bf16* __restrict__ s_t)
{
    __shared__ __bf16 buf0[64 * 136];   // Xt (stride 72) then H2t (stride 136)
    __shared__ __bf16 un[128 * 72];     // H1t (stride 104) then OutT (stride 72)
    __shared__ float  bl[672];
    __bf16* H1t  = un;                  // 64 x 104 fits in 128*72
    __bf16* OutT = un;                  // 128 x 72
    float* b1l = bl;       float* p1l = bl + 96;
    float* b2l = bl + 192; float* p2l = bl + 304;
    float* bml = bl + 416; float* bsl = bl + 544;

    const int t = threadIdx.x, lane = t & 63, wid = t >> 6;
    const int b = blockIdx.y;
    const int p0 = blockIdx.x * 64;

    for (int i = t; i < 96; i += 256)  { b1l[i] = (i < 83)  ? b1[i] : 0.f; p1l[i] = (i < 83)  ? p1[i] : 0.f; }
    for (int i = t; i < 112; i += 256) { b2l[i] = (i < 102) ? b2[i] : 0.f; p2l[i] = (i < 102) ? p2[i] : 0.f; }
    for (int i = t; i < 128; i += 256) { bml[i] = bm[i]; bsl[i] = bs[i]; }

    {
        const int p = t & 63;
        const int cg = t >> 6;     // 0..3
#pragma unroll 4
        for (int it = 0; it < 16; it++) {
            int c = it * 4 + cg;
            buf0[p * 72 + c] = (__bf16)x[((size_t)b * 64 + c) * 8192 + p0 + p];
        }
    }
    __syncthreads();

    const int quad4 = (lane >> 4) << 2;
    const int l15 = lane & 15;

    // shortcut S = WS*X + bs  (8 mt x 4 nt)
    for (int tt = wid; tt < 32; tt += 4) {
        int mt = tt >> 2, nt = tt & 3;
        f32x4 a = mfma_tile<2>(WSp, 64, mt, buf0, 72, nt, lane);
        int ocb = mt * 16 + quad4;
        int pos = nt * 16 + l15;
        bf16x4 ov;
#pragma unroll
        for (int r = 0; r < 4; r++) ov[r] = (__bf16)(a[r] + bsl[ocb + r]);
        *(bf16x4*)(s_t + ((size_t)b * 8192 + p0 + pos) * 128 + ocb) = ov;
    }
    // H1 = cprelu(W1*X + b1)  (6 mt x 4 nt)
    for (int tt = wid; tt < 24; tt += 4) {
        int mt = tt >> 2, nt = tt & 3;
        f32x4 a = mfma_tile<2>(W1p, 64, mt, buf0, 72, nt, lane);
        int ocb = mt * 16 + quad4;
        int pos = nt * 16 + l15;
        bf16x4 ov;
#pragma unroll
        for (int r = 0; r < 4; r++) {
            float v = a[r] + b1l[ocb + r];
            v = (v >= 0.f) ? v : v * p1l[ocb + r];
            ov[r] = (__bf16)((v - PM) * PIS);
        }
        *(bf16x4*)(&H1t[pos * 104 + ocb]) = ov;
    }
    __syncthreads();

    // H2 = cprelu(W2*H1 + b2)  (7 mt x 4 nt), into buf0 (Xt dead)
    for (int tt = wid; tt < 28; tt += 4) {
        int mt = tt >> 2, nt = tt & 3;
        f32x4 a = mfma_tile<3>(W2p, 96, mt, H1t, 104, nt, lane);
        int ocb = mt * 16 + quad4;
        int pos = nt * 16 + l15;
        bf16x4 ov;
#pragma unroll
        for (int r = 0; r < 4; r++) {
            float v = a[r] + b2l[ocb + r];
            v = (v >= 0.f) ? v : v * p2l[ocb + r];
            ov[r] = (__bf16)((v - PM) * PIS);
        }
        *(bf16x4*)(&buf0[pos * 136 + ocb]) = ov;
    }
    // zero H2 pad channels 112..127
    for (int i = t; i < 64 * 16; i += 256) {
        int pos = i >> 4, c = 112 + (i & 15);
        buf0[pos * 136 + c] = (__bf16)0.f;
    }
    __syncthreads();   // also: H1t reads done before OutT overwrites region

    // H3 = WM*H2 + bm  (8 mt x 4 nt) -> OutT[ch][pos] in LDS
    for (int tt = wid; tt < 32; tt += 4) {
        int mt = tt >> 2, nt = tt & 3;
        f32x4 a = mfma_tile<4>(WMp, 128, mt, buf0, 136, nt, lane);
        int ocb = mt * 16 + quad4;
        int pos = nt * 16 + l15;
#pragma unroll
        for (int r = 0; r < 4; r++)
            OutT[(ocb + r) * 72 + pos] = (__bf16)(a[r] + bml[ocb + r]);
    }
    __syncthreads();

    // coalesced OutT -> h3 (bf16x8 per lane, 128B per channel row)
#pragma unroll
    for (int it = 0; it < 4; it++) {
        int lin = it * 256 + t;       // 0..1023
        int ch = lin >> 3, pc = lin & 7;
        bf16x8 v = *(const bf16x8*)(OutT + ch * 72 + pc * 8);
        *(bf16x8*)(h3 + ((size_t)b * 128 + ch) * 8192 + p0 + pc * 8) = v;
    }
}

// ---------------------------------------------------------------- k_gemm
// out[2048,4096] = combine(A[2048,8192](bf16) x B[4096,bstride](bf16)).
// 128(M) x 64(N) tile, BK=64 (24.5KB LDS), full K=8192, grid 1024 blocks
// -> 4 blocks/CU (the r3 regression was grid-capped 2/CU at 512 blocks).
// XOR swizzle: 16B chunk (row, c) of a 64-elem row stored at c ^ (row & 7).
// Fused combine epilogue with REGISTER gather (no sp LDS): each thread
// needs only 2 cols x 16 channels of the pooled shortcut = 8 bf16x4 reads.
// XCD-chunked swizzle: each XCD gets 2 batches x all 64 N-tiles, so its
// 4 MB A-panel set stays L2-resident; B (67 MB) is served from L3.
__global__ __launch_bounds__(256, 4) void k_gemm(const __bf16* __restrict__ A,
                                                 const __bf16* __restrict__ B,
                                                 size_t bstride,
                                                 float* __restrict__ out,
                                                 const __bf16* __restrict__ s_t,
                                                 const int* __restrict__ idx,
                                                 const int* __restrict__ cnt,
                                                 const float* __restrict__ p3)
{
    __shared__ __bf16 la[128 * 64];     // A tile: 128 rows (channels)
    __shared__ __bf16 lb[64 * 64];      // B tile: 64 rows (out positions)

    const int t = threadIdx.x;
    const int lane = t & 63;
    const int wid = t >> 6;

    // XCD-chunked bijective swizzle (1024 blocks, 1024 % 8 == 0)
    const int hw  = blockIdx.y * 64 + blockIdx.x;     // dispatch-linear id
    const int nid = (hw & 7) * 128 + (hw >> 3);       // chunk per XCD
    const int tMi = nid >> 6;                         // batch 0..15
    const int tM  = tMi * 128;
    const int tN  = (nid & 63) * 64;

    const int wm2 = (wid & 1) * 64;     // M half owned by wave
    const int wn2 = (wid >> 1) * 32;    // N half owned by wave

    f32x4 acc[4][2];
    const f32x4 zero = {0.f, 0.f, 0.f, 0.f};
#pragma unroll
    for (int i = 0; i < 4; i++)
#pragma unroll
        for (int j = 0; j < 2; j++) acc[i][j] = zero;

    // staging: issue i covers rows i*32..i*32+31 (A: 4 issues, B: 2)
    const int tr = t >> 3;                    // 0..31
    const int sc = (t & 7) ^ (tr & 7);        // swizzled global chunk
    const __bf16* pA[4];
    const __bf16* pB[2];
#pragma unroll
    for (int i = 0; i < 4; i++)
        pA[i] = A + (size_t)(tM + i * 32 + tr) * 8192 + sc * 8;
#pragma unroll
    for (int i = 0; i < 2; i++)
        pB[i] = B + (size_t)(tN + i * 32 + tr) * bstride + sc * 8;

    const int l15 = lane & 15;
    const int q = lane >> 4;
    int aoff[4], boff[2];
#pragma unroll
    for (int i = 0; i < 4; i++) {
        int row = wm2 + i * 16 + l15;
        aoff[i] = row * 64 + ((q ^ (row & 7)) * 8);
    }
#pragma unroll
    for (int j = 0; j < 2; j++) {
        int row = wn2 + j * 16 + l15;
        boff[j] = row * 64 + ((q ^ (row & 7)) * 8);
    }

    for (int it = 0; it < 128; it++) {
#pragma unroll
        for (int i = 0; i < 4; i++) load_lds16(pA[i], la + (i * 256 + t) * 8);
#pragma unroll
        for (int i = 0; i < 2; i++) load_lds16(pB[i], lb + (i * 256 + t) * 8);
#pragma unroll
        for (int i = 0; i < 4; i++) pA[i] += 64;
#pragma unroll
        for (int i = 0; i < 2; i++) pB[i] += 64;
        __syncthreads();
#pragma unroll
        for (int ks = 0; ks < 2; ks++) {
            bf16x8 af[4], bfr[2];
#pragma unroll
            for (int i = 0; i < 4; i++) af[i]  = *(const bf16x8*)(la + (aoff[i] ^ (ks << 5)));
#pragma unroll
            for (int j = 0; j < 2; j++) bfr[j] = *(const bf16x8*)(lb + (boff[j] ^ (ks << 5)));
#pragma unroll
            for (int i = 0; i < 4; i++)
#pragma unroll
                for (int j = 0; j < 2; j++)
                    acc[i][j] = __builtin_amdgcn_mfma_f32_16x16x32_bf16(af[i], bfr[j], acc[i][j], 0, 0, 0);
        }
        __syncthreads();
    }

    // ---- fused combine epilogue (register gather, no LDS reuse) ----
    const int quad4 = q * 4;

    // p3 for this thread's 16 channels
    f32x4 pw[4];
#pragma unroll
    for (int i = 0; i < 4; i++)
        pw[i] = *(const f32x4*)(p3 + wm2 + i * 16 + quad4);

    // pooled shortcut: spv[j][i][r] = sum_{k<cnt[col]} s_t[b, idx_k, c]
    f32x4 spv[2][4];
#pragma unroll
    for (int j = 0; j < 2; j++)
#pragma unroll
        for (int i = 0; i < 4; i++) spv[j][i] = zero;

    const __bf16* sbase = s_t + ((size_t)tMi * 8192) * 128;
#pragma unroll
    for (int j = 0; j < 2; j++) {
        const int col = tN + wn2 + j * 16 + l15;
        const int n = cnt[col];
        for (int k = 0; k < n; k++) {
            const __bf16* row = sbase + (size_t)idx[col * 16 + k] * 128;
#pragma unroll
            for (int i = 0; i < 4; i++) {
                bf16x4 v = *(const bf16x4*)(row + wm2 + i * 16 + quad4);
#pragma unroll
                for (int r = 0; r < 4; r++) spv[j][i][r] += (float)v[r];
            }
        }
    }

#pragma unroll
    for (int i = 0; i < 4; i++) {
        const int gm = tM + wm2 + i * 16 + quad4;
#pragma unroll
        for (int j = 0; j < 2; j++) {
            const int gn = tN + wn2 + j * 16 + l15;
#pragma unroll
            for (int r = 0; r < 4; r++) {
                float v = acc[i][j][r];
                float y = (v >= 0.f) ? v : v * pw[i][r];
                y = (y - PM) * PIS;
                out[(size_t)(gm + r) * 4096 + gn] = spv[j][i][r] * RHALF + y * RHALF;
            }
        }
    }
}

// ---------------------------------------------------------------- launch
extern "C" void kernel_launch(void* const* d_in, const int* in_sizes, int n_in,
                              void* d_out, int out_size, void* d_ws, size_t ws_size,
                              hipStream_t stream) {
    (void)in_sizes; (void)n_in; (void)out_size;
    const float* x    = (const float*)d_in[0];
    const float* conn = (const float*)d_in[1];
    const float* w1   = (const float*)d_in[2];
    const float* b1   = (const float*)d_in[3];
    const float* p1   = (const float*)d_in[4];
    const float* w2   = (const float*)d_in[5];
    const float* b2   = (const float*)d_in[6];
    const float* p2   = (const float*)d_in[7];
    const float* wm   = (const float*)d_in[8];
    const float* bm   = (const float*)d_in[9];
    const float* p3   = (const float*)d_in[10];
    const float* wsw  = (const float*)d_in[11];
    const float* bs   = (const float*)d_in[12];
    float* out = (float*)d_out;

    char* ws = (char*)d_ws;
    __bf16* h3  = (__bf16*)(ws);                          // 33,554,432 B
    __bf16* s_t = (__bf16*)(ws + 33554432);               // 33,554,432 B
    __bf16* W1p = (__bf16*)(ws + 67108864);               // 12,288
    __bf16* W2p = (__bf16*)(ws + 67108864 + 12288);       // 21,504
    __bf16* WMp = (__bf16*)(ws + 67108864 + 33792);       // 32,768
    __bf16* WSp = (__bf16*)(ws + 67108864 + 66560);       // 16,384
    int* idx = (int*)(ws + 67108864 + 82944);             // 262,144
    int* cnt = (int*)(ws + 67108864 + 82944 + 262144);    // 16,384
    const size_t connb_off = 67108864 + 82944 + 262144 + 16384;   // 67,470,336

    __bf16* connb;
    size_t  cstride;
    if (ws_size >= connb_off + (size_t)4096 * 8192 * 2) {
        connb = (__bf16*)(ws + connb_off);
        cstride = 8192;
    } else {
        connb = (__bf16*)const_cast<float*>(conn);
        cstride = 16384;   // bf16 row packed into first half of its fp32 row
    }

    k_prep<<<32, 256, 0, stream>>>(w1, w2, wm, wsw, W1p, W2p, WMp, WSp);
    k_conv<<<4096, 256, 0, stream>>>(conn, connb, cstride, cnt, idx);
    k_chain<<<dim3(8192 / 64, 16), 256, 0, stream>>>(x, b1, p1, b2, p2, bm, bs,
                                                     W1p, W2p, WMp, WSp, h3, s_t);
    k_gemm<<<dim3(64, 16), 256, 0, stream>>>(h3, connb, cstride, out, s_t, idx, cnt, p3);
}

// Round 5
// 466.813 us; speedup vs baseline: 1.0992x; 1.0992x over previous
//
#include <hip/hip_runtime.h>
#include <hip/hip_bf16.h>
#include <stdint.h>

using bf16x8 = __attribute__((ext_vector_type(8))) __bf16;
using bf16x4 = __attribute__((ext_vector_type(4))) __bf16;
using f32x4  = __attribute__((ext_vector_type(4))) float;

typedef const uint32_t __attribute__((address_space(1)))* gas_ptr;
typedef uint32_t __attribute__((address_space(3)))* las_ptr;

__device__ __forceinline__ void load_lds16(const void* g, void* l) {
    __builtin_amdgcn_global_load_lds((gas_ptr)g, (las_ptr)l, 16, 0, 0);
}

// cprelu post-normalization constants (PRELU_INIT = 0.25)
#define PM  0.29920671030107454f
#define PIS 1.5046096f
#define RHALF 0.70710678118654752f

// ---------------------------------------------------------------- k_prep
__global__ __launch_bounds__(256) void k_prep(const float* __restrict__ w1,
                                              const float* __restrict__ w2,
                                              const float* __restrict__ wm,
                                              const float* __restrict__ wsw,
                                              __bf16* __restrict__ W1p,
                                              __bf16* __restrict__ W2p,
                                              __bf16* __restrict__ WMp,
                                              __bf16* __restrict__ WSp)
{
    const int id = blockIdx.x * 256 + threadIdx.x;
    const int stride = gridDim.x * 256;
    for (int i = id; i < 96 * 64; i += stride) {
        int oc = i >> 6, ic = i & 63;
        W1p[i] = (__bf16)((oc < 83) ? w1[oc * 64 + ic] : 0.f);
    }
    for (int i = id; i < 112 * 96; i += stride) {
        int oc = i / 96, ic = i % 96;
        W2p[i] = (__bf16)((oc < 102 && ic < 83) ? w2[oc * 83 + ic] : 0.f);
    }
    for (int i = id; i < 128 * 128; i += stride) {
        int oc = i >> 7, ic = i & 127;
        WMp[i] = (__bf16)((ic < 102) ? wm[oc * 102 + ic] : 0.f);
    }
    for (int i = id; i < 128 * 64; i += stride) {
        WSp[i] = (__bf16)wsw[i];
    }
}

// ---------------------------------------------------------------- mfma_tile
template<int KS>
__device__ __forceinline__ f32x4 mfma_tile(const __bf16* __restrict__ W, int wstride, int mt,
                                           const __bf16* B, int bstride, int nt, int lane)
{
    f32x4 acc = {0.f, 0.f, 0.f, 0.f};
    const int l15 = lane & 15;
    const int kg  = (lane >> 4) << 3;
    const __bf16* wp = W + (mt * 16 + l15) * wstride + kg;
    const __bf16* bp = B + (nt * 16 + l15) * bstride + kg;
#pragma unroll
    for (int ks = 0; ks < KS; ks++) {
        bf16x8 av = *(const bf16x8*)(wp + ks * 32);
        bf16x8 bv = *(const bf16x8*)(bp + ks * 32);
        acc = __builtin_amdgcn_mfma_f32_16x16x32_bf16(av, bv, acc, 0, 0, 0);
    }
    return acc;
}

// ---------------------------------------------------------------- k_cc
// Fused k_conv (4096 blocks) + k_chain (2048 blocks), grid-partitioned and
// interleaved 2:1 (conv,conv,chain) so memory-bound conv co-schedules with
// latency/MFMA-bound chain (r3: measured ~30 us win vs split launches).
__global__ __launch_bounds__(256) void k_cc(
    // conv args
    const float* __restrict__ conn, __bf16* __restrict__ cb, size_t rowstride,
    int* __restrict__ cnt, int* __restrict__ idx,
    // chain args
    const float* __restrict__ x,
    const float* __restrict__ b1, const float* __restrict__ p1,
    const float* __restrict__ b2, const float* __restrict__ p2,
    const float* __restrict__ bm, const float* __restrict__ bs,
    const __bf16* __restrict__ W1p, const __bf16* __restrict__ W2p,
    const __bf16* __restrict__ WMp, const __bf16* __restrict__ WSp,
    __bf16* __restrict__ h3, __bf16* __restrict__ s_t)
{
    __shared__ __align__(16) char pool[38528];
    const int t = threadIdx.x;
    const int bx = blockIdx.x;
    const int r3 = bx % 3;
    const int g  = bx / 3;

    if (r3 < 2) {
        // ------------------------------------------------ conv path
        const int o = 2 * g + r3;              // 0..4095
        float* wmax = (float*)pool;            // 16 B
        int*   scnt = (int*)(pool + 16);
        const float* row = conn + (size_t)o * 8192;
        float4 v[8];
        float m = -1e30f;
#pragma unroll
        for (int q = 0; q < 8; q++) {
            v[q] = *(const float4*)(row + (size_t)(q * 256 + t) * 4);
            m = fmaxf(m, fmaxf(fmaxf(v[q].x, v[q].y), fmaxf(v[q].z, v[q].w)));
        }
        __syncthreads();   // all reads drained before in-place overwrite
        __bf16* drow = cb + (size_t)o * rowstride;
#pragma unroll
        for (int q = 0; q < 8; q++) {
            bf16x4 w;
            w[0] = (__bf16)v[q].x; w[1] = (__bf16)v[q].y;
            w[2] = (__bf16)v[q].z; w[3] = (__bf16)v[q].w;
            *(bf16x4*)(drow + (size_t)(q * 256 + t) * 4) = w;
        }
#pragma unroll
        for (int off = 32; off > 0; off >>= 1) m = fmaxf(m, __shfl_down(m, off, 64));
        if ((t & 63) == 0) wmax[t >> 6] = m;
        if (t == 0) *scnt = 0;
        __syncthreads();
        const float rmax = fmaxf(fmaxf(wmax[0], wmax[1]), fmaxf(wmax[2], wmax[3]));
#pragma unroll
        for (int q = 0; q < 8; q++) {
            float vv[4] = {v[q].x, v[q].y, v[q].z, v[q].w};
#pragma unroll
            for (int e = 0; e < 4; e++) {
                if (vv[e] >= rmax) {
                    int p = atomicAdd(scnt, 1);
                    if (p < 16) idx[o * 16 + p] = (q * 256 + t) * 4 + e;
                }
            }
        }
        __syncthreads();
        if (t == 0) cnt[o] = *scnt < 16 ? *scnt : 16;
        return;
    }

    // ---------------------------------------------------- chain path
    const int b  = g >> 7;                 // 0..15
    const int p0 = (g & 127) * 64;         // 0..8128
    __bf16* buf0 = (__bf16*)pool;          // 64*136 = 17408 B
    __bf16* un   = (__bf16*)(pool + 17408);// 128*72 = 18432 B
    float*  bl   = (float*)(pool + 35840); // 672 floats = 2688 B
    __bf16* H1t  = un;                     // 64 x 104 fits in 128*72
    __bf16* OutT = un;                     // 128 x 72
    float* b1l = bl;       float* p1l = bl + 96;
    float* b2l = bl + 192; float* p2l = bl + 304;
    float* bml = bl + 416; float* bsl = bl + 544;

    const int lane = t & 63, wid = t >> 6;

    for (int i = t; i < 96; i += 256)  { b1l[i] = (i < 83)  ? b1[i] : 0.f; p1l[i] = (i < 83)  ? p1[i] : 0.f; }
    for (int i = t; i < 112; i += 256) { b2l[i] = (i < 102) ? b2[i] : 0.f; p2l[i] = (i < 102) ? p2[i] : 0.f; }
    for (int i = t; i < 128; i += 256) { bml[i] = bm[i]; bsl[i] = bs[i]; }

    {
        // vectorized x staging: float4 along positions, transpose into LDS
        const int pg = (t & 15) * 4;        // position base 0..60
        const int c0 = t >> 4;              // 0..15
#pragma unroll
        for (int it = 0; it < 4; it++) {
            int c = it * 16 + c0;
            float4 xv = *(const float4*)(x + ((size_t)b * 64 + c) * 8192 + p0 + pg);
            buf0[(pg + 0) * 72 + c] = (__bf16)xv.x;
            buf0[(pg + 1) * 72 + c] = (__bf16)xv.y;
            buf0[(pg + 2) * 72 + c] = (__bf16)xv.z;
            buf0[(pg + 3) * 72 + c] = (__bf16)xv.w;
        }
    }
    __syncthreads();

    const int quad4 = (lane >> 4) << 2;
    const int l15 = lane & 15;

    // shortcut S = WS*X + bs  (8 mt x 4 nt)
    for (int tt = wid; tt < 32; tt += 4) {
        int mt = tt >> 2, nt = tt & 3;
        f32x4 a = mfma_tile<2>(WSp, 64, mt, buf0, 72, nt, lane);
        int ocb = mt * 16 + quad4;
        int pos = nt * 16 + l15;
        bf16x4 ov;
#pragma unroll
        for (int r = 0; r < 4; r++) ov[r] = (__bf16)(a[r] + bsl[ocb + r]);
        *(bf16x4*)(s_t + ((size_t)b * 8192 + p0 + pos) * 128 + ocb) = ov;
    }
    // H1 = cprelu(W1*X + b1)  (6 mt x 4 nt)
    for (int tt = wid; tt < 24; tt += 4) {
        int mt = tt >> 2, nt = tt & 3;
        f32x4 a = mfma_tile<2>(W1p, 64, mt, buf0, 72, nt, lane);
        int ocb = mt * 16 + quad4;
        int pos = nt * 16 + l15;
        bf16x4 ov;
#pragma unroll
        for (int r = 0; r < 4; r++) {
            float v = a[r] + b1l[ocb + r];
            v = (v >= 0.f) ? v : v * p1l[ocb + r];
            ov[r] = (__bf16)((v - PM) * PIS);
        }
        *(bf16x4*)(&H1t[pos * 104 + ocb]) = ov;
    }
    __syncthreads();

    // H2 = cprelu(W2*H1 + b2)  (7 mt x 4 nt), into buf0 (Xt dead)
    for (int tt = wid; tt < 28; tt += 4) {
        int mt = tt >> 2, nt = tt & 3;
        f32x4 a = mfma_tile<3>(W2p, 96, mt, H1t, 104, nt, lane);
        int ocb = mt * 16 + quad4;
        int pos = nt * 16 + l15;
        bf16x4 ov;
#pragma unroll
        for (int r = 0; r < 4; r++) {
            float v = a[r] + b2l[ocb + r];
            v = (v >= 0.f) ? v : v * p2l[ocb + r];
            ov[r] = (__bf16)((v - PM) * PIS);
        }
        *(bf16x4*)(&buf0[pos * 136 + ocb]) = ov;
    }
    // zero H2 pad channels 112..127
    for (int i = t; i < 64 * 16; i += 256) {
        int pos = i >> 4, c = 112 + (i & 15);
        buf0[pos * 136 + c] = (__bf16)0.f;
    }
    __syncthreads();   // also: H1t reads done before OutT overwrites region

    // H3 = WM*H2 + bm  (8 mt x 4 nt) -> OutT[ch][pos] in LDS
    for (int tt = wid; tt < 32; tt += 4) {
        int mt = tt >> 2, nt = tt & 3;
        f32x4 a = mfma_tile<4>(WMp, 128, mt, buf0, 136, nt, lane);
        int ocb = mt * 16 + quad4;
        int pos = nt * 16 + l15;
#pragma unroll
        for (int r = 0; r < 4; r++)
            OutT[(ocb + r) * 72 + pos] = (__bf16)(a[r] + bml[ocb + r]);
    }
    __syncthreads();

    // coalesced OutT -> h3 (bf16x8 per lane, 128B per channel row)
#pragma unroll
    for (int it = 0; it < 4; it++) {
        int lin = it * 256 + t;       // 0..1023
        int ch = lin >> 3, pc = lin & 7;
        bf16x8 v = *(const bf16x8*)(OutT + ch * 72 + pc * 8);
        *(bf16x8*)(h3 + ((size_t)b * 128 + ch) * 8192 + p0 + pc * 8) = v;
    }
}

// ---------------------------------------------------------------- k_gemm
// out[2048,4096] = combine(A[2048,8192](bf16) x B[4096,bstride](bf16)).
// r3's fused 128x128 tile / BK=64 / full-K structure (178 us, FETCH 220 MB)
// upgraded to 512 threads = 8 waves (2M x 4N, 64x32 per wave): the 512-block
// grid caps residency at 2 blocks/CU, so 8 waves/block doubles wave
// parallelism to 16 waves/CU (r3's MfmaUtil-32% cause was 8 waves/CU).
// XOR swizzle: 16B chunk (row, c) of a 64-elem row stored at c ^ (row & 7).
// Epilogue fusion: tM spans exactly one batch's 128 channels -> cprelu(p3),
// argmax-pool gather of s_t via idx/cnt into LDS sp, blend, final out.
__global__ __launch_bounds__(512, 2) void k_gemm(const __bf16* __restrict__ A,
                                                 const __bf16* __restrict__ B,
                                                 size_t bstride,
                                                 float* __restrict__ out,
                                                 const __bf16* __restrict__ s_t,
                                                 const int* __restrict__ idx,
                                                 const int* __restrict__ cnt,
                                                 const float* __restrict__ p3)
{
    __shared__ __align__(16) char pool[66560];
    __bf16* la = (__bf16*)pool;              // 128*64 bf16 = 16384 B
    __bf16* lb = (__bf16*)(pool + 16384);    // 128*64 bf16 = 16384 B
    float*  sp = (float*)pool;               // [128][129] = 66048 B (after loop)
    float* p3l = (float*)(pool + 66048);     // 512 B

    const int t = threadIdx.x;               // 0..511
    const int lane = t & 63;
    const int wid = t >> 6;                  // 0..7
    const int tMi = blockIdx.y;              // batch 0..15
    const int tM = tMi * 128;
    const int tN = blockIdx.x * 128;
    const int wm2 = (wid & 1) * 64;          // M half owned by wave
    const int wn2 = (wid >> 1) * 32;         // N quarter owned by wave

    f32x4 acc[4][2];
    const f32x4 zero = {0.f, 0.f, 0.f, 0.f};
#pragma unroll
    for (int i = 0; i < 4; i++)
#pragma unroll
        for (int j = 0; j < 2; j++) acc[i][j] = zero;

    // staging: 2 issues per matrix; issue i covers rows i*64..i*64+63
    const int tr = t >> 3;                    // 0..63
    const int sc = (t & 7) ^ (tr & 7);        // swizzled global chunk
    const __bf16* pA[2];
    const __bf16* pB[2];
#pragma unroll
    for (int i = 0; i < 2; i++) {
        pA[i] = A + (size_t)(tM + i * 64 + tr) * 8192 + sc * 8;
        pB[i] = B + (size_t)(tN + i * 64 + tr) * bstride + sc * 8;
    }

    const int l15 = lane & 15;
    const int q = lane >> 4;
    int aoff[4], boff[2];
#pragma unroll
    for (int i = 0; i < 4; i++) {
        int row = wm2 + i * 16 + l15;
        aoff[i] = row * 64 + ((q ^ (row & 7)) * 8);
    }
#pragma unroll
    for (int j = 0; j < 2; j++) {
        int row = wn2 + j * 16 + l15;
        boff[j] = row * 64 + ((q ^ (row & 7)) * 8);
    }

    for (int it = 0; it < 128; it++) {
#pragma unroll
        for (int i = 0; i < 2; i++) load_lds16(pA[i], la + (i * 512 + t) * 8);
#pragma unroll
        for (int i = 0; i < 2; i++) load_lds16(pB[i], lb + (i * 512 + t) * 8);
#pragma unroll
        for (int i = 0; i < 2; i++) { pA[i] += 64; pB[i] += 64; }
        __syncthreads();
#pragma unroll
        for (int ks = 0; ks < 2; ks++) {
            bf16x8 af[4], bfr[2];
#pragma unroll
            for (int i = 0; i < 4; i++) af[i]  = *(const bf16x8*)(la + (aoff[i] ^ (ks << 5)));
#pragma unroll
            for (int j = 0; j < 2; j++) bfr[j] = *(const bf16x8*)(lb + (boff[j] ^ (ks << 5)));
#pragma unroll
            for (int i = 0; i < 4; i++)
#pragma unroll
                for (int j = 0; j < 2; j++)
                    acc[i][j] = __builtin_amdgcn_mfma_f32_16x16x32_bf16(af[i], bfr[j], acc[i][j], 0, 0, 0);
        }
        __syncthreads();
    }
    // loop ends with __syncthreads(): all LDS reads done, LDS-DMA drained ->
    // pool is safe to reuse.

    // ---- shortcut gather: sp[l][c] = sum_{k<cnt[tN+l]} s_t[b, idx_k, c]
    {
        const int l = t >> 2;                 // col-in-tile 0..127
        const int part = t & 3;               // channel quarter
        const int col = tN + l;
        const int n = cnt[col];
        const __bf16* base = s_t + ((size_t)tMi * 8192) * 128 + part * 32;
        float* spr = sp + l * 129 + part * 32;
        {
            const __bf16* row = base + (size_t)idx[col * 16] * 128;
#pragma unroll
            for (int j = 0; j < 4; j++) {
                bf16x8 v = *(const bf16x8*)(row + j * 8);
#pragma unroll
                for (int u = 0; u < 8; u++) spr[j * 8 + u] = (float)v[u];
            }
        }
        for (int k = 1; k < n; k++) {
            const __bf16* row = base + (size_t)idx[col * 16 + k] * 128;
#pragma unroll
            for (int j = 0; j < 4; j++) {
                bf16x8 v = *(const bf16x8*)(row + j * 8);
#pragma unroll
                for (int u = 0; u < 8; u++) spr[j * 8 + u] += (float)v[u];
            }
        }
        if (t < 128) p3l[t] = p3[t];
    }
    __syncthreads();

    // ---- fused combine epilogue
    const int quad4 = q * 4;
#pragma unroll
    for (int i = 0; i < 4; i++) {
        int gm = tM + wm2 + i * 16 + quad4;
#pragma unroll
        for (int j = 0; j < 2; j++) {
            int gn = tN + wn2 + j * 16 + l15;
            int colT = wn2 + j * 16 + l15;
#pragma unroll
            for (int r = 0; r < 4; r++) {
                int c = wm2 + i * 16 + quad4 + r;      // channel 0..127
                float v = acc[i][j][r];
                float pw = p3l[c];
                float y = (v >= 0.f) ? v : v * pw;
                y = (y - PM) * PIS;
                out[(size_t)(gm + r) * 4096 + gn] = sp[colT * 129 + c] * RHALF + y * RHALF;
            }
        }
    }
}

// ---------------------------------------------------------------- launch
extern "C" void kernel_launch(void* const* d_in, const int* in_sizes, int n_in,
                              void* d_out, int out_size, void* d_ws, size_t ws_size,
                              hipStream_t stream) {
    (void)in_sizes; (void)n_in; (void)out_size;
    const float* x    = (const float*)d_in[0];
    const float* conn = (const float*)d_in[1];
    const float* w1   = (const float*)d_in[2];
    const float* b1   = (const float*)d_in[3];
    const float* p1   = (const float*)d_in[4];
    const float* w2   = (const float*)d_in[5];
    const float* b2   = (const float*)d_in[6];
    const float* p2   = (const float*)d_in[7];
    const float* wm   = (const float*)d_in[8];
    const float* bm   = (const float*)d_in[9];
    const float* p3   = (const float*)d_in[10];
    const float* wsw  = (const float*)d_in[11];
    const float* bs   = (const float*)d_in[12];
    float* out = (float*)d_out;

    char* ws = (char*)d_ws;
    __bf16* h3  = (__bf16*)(ws);                          // 33,554,432 B
    __bf16* s_t = (__bf16*)(ws + 33554432);               // 33,554,432 B
    __bf16* W1p = (__bf16*)(ws + 67108864);               // 12,288
    __bf16* W2p = (__bf16*)(ws + 67108864 + 12288);       // 21,504
    __bf16* WMp = (__bf16*)(ws + 67108864 + 33792);       // 32,768
    __bf16* WSp = (__bf16*)(ws + 67108864 + 66560);       // 16,384
    int* idx = (int*)(ws + 67108864 + 82944);             // 262,144
    int* cnt = (int*)(ws + 67108864 + 82944 + 262144);    // 16,384
    const size_t connb_off = 67108864 + 82944 + 262144 + 16384;   // 67,470,336

    __bf16* connb;
    size_t  cstride;
    if (ws_size >= connb_off + (size_t)4096 * 8192 * 2) {
        connb = (__bf16*)(ws + connb_off);
        cstride = 8192;
    } else {
        connb = (__bf16*)const_cast<float*>(conn);
        cstride = 16384;   // bf16 row packed into first half of its fp32 row
    }

    k_prep<<<32, 256, 0, stream>>>(w1, w2, wm, wsw, W1p, W2p, WMp, WSp);
    k_cc<<<6144, 256, 0, stream>>>(conn, connb, cstride, cnt, idx,
                                   x, b1, p1, b2, p2, bm, bs,
                                   W1p, W2p, WMp, WSp, h3, s_t);
    k_gemm<<<dim3(32, 16), 512, 0, stream>>>(h3, connb, cstride, out, s_t, idx, cnt, p3);
}

// Round 6
// 465.179 us; speedup vs baseline: 1.1031x; 1.0035x over previous
//
#include <hip/hip_runtime.h>
#include <hip/hip_bf16.h>
#include <stdint.h>

using bf16x8 = __attribute__((ext_vector_type(8))) __bf16;
using bf16x4 = __attribute__((ext_vector_type(4))) __bf16;
using f32x4  = __attribute__((ext_vector_type(4))) float;

typedef const uint32_t __attribute__((address_space(1)))* gas_ptr;
typedef uint32_t __attribute__((address_space(3)))* las_ptr;

__device__ __forceinline__ void load_lds16(const void* g, void* l) {
    __builtin_amdgcn_global_load_lds((gas_ptr)g, (las_ptr)l, 16, 0, 0);
}

// cprelu post-normalization constants (PRELU_INIT = 0.25)
#define PM  0.29920671030107454f
#define PIS 1.5046096f
#define RHALF 0.70710678118654752f

// ---------------------------------------------------------------- k_prep
__global__ __launch_bounds__(256) void k_prep(const float* __restrict__ w1,
                                              const float* __restrict__ w2,
                                              const float* __restrict__ wm,
                                              const float* __restrict__ wsw,
                                              __bf16* __restrict__ W1p,
                                              __bf16* __restrict__ W2p,
                                              __bf16* __restrict__ WMp,
                                              __bf16* __restrict__ WSp)
{
    const int id = blockIdx.x * 256 + threadIdx.x;
    const int stride = gridDim.x * 256;
    for (int i = id; i < 96 * 64; i += stride) {
        int oc = i >> 6, ic = i & 63;
        W1p[i] = (__bf16)((oc < 83) ? w1[oc * 64 + ic] : 0.f);
    }
    for (int i = id; i < 112 * 96; i += stride) {
        int oc = i / 96, ic = i % 96;
        W2p[i] = (__bf16)((oc < 102 && ic < 83) ? w2[oc * 83 + ic] : 0.f);
    }
    for (int i = id; i < 128 * 128; i += stride) {
        int oc = i >> 7, ic = i & 127;
        WMp[i] = (__bf16)((ic < 102) ? wm[oc * 102 + ic] : 0.f);
    }
    for (int i = id; i < 128 * 64; i += stride) {
        WSp[i] = (__bf16)wsw[i];
    }
}

// ---------------------------------------------------------------- mfma_tile
template<int KS>
__device__ __forceinline__ f32x4 mfma_tile(const __bf16* __restrict__ W, int wstride, int mt,
                                           const __bf16* B, int bstride, int nt, int lane)
{
    f32x4 acc = {0.f, 0.f, 0.f, 0.f};
    const int l15 = lane & 15;
    const int kg  = (lane >> 4) << 3;
    const __bf16* wp = W + (mt * 16 + l15) * wstride + kg;
    const __bf16* bp = B + (nt * 16 + l15) * bstride + kg;
#pragma unroll
    for (int ks = 0; ks < KS; ks++) {
        bf16x8 av = *(const bf16x8*)(wp + ks * 32);
        bf16x8 bv = *(const bf16x8*)(bp + ks * 32);
        acc = __builtin_amdgcn_mfma_f32_16x16x32_bf16(av, bv, acc, 0, 0, 0);
    }
    return acc;
}

// ---------------------------------------------------------------- k_cc
// Fused k_conv (4096 blocks) + k_chain (2048 blocks), grid-partitioned and
// interleaved 2:1 (conv,conv,chain) so memory-bound conv co-schedules with
// latency/MFMA-bound chain (r3: measured ~30 us win vs split launches).
// R6: chain's shortcut S is now transposed through LDS (St in `un`) and
// flushed to s_t as full-wave 1KB contiguous stores — the old path wrote
// 8B per lane at 256B stride (4M scattered stores, ~8x HBM write
// amplification on a 32MB tensor).
__global__ __launch_bounds__(256) void k_cc(
    // conv args
    const float* __restrict__ conn, __bf16* __restrict__ cb, size_t rowstride,
    int* __restrict__ cnt, int* __restrict__ idx,
    // chain args
    const float* __restrict__ x,
    const float* __restrict__ b1, const float* __restrict__ p1,
    const float* __restrict__ b2, const float* __restrict__ p2,
    const float* __restrict__ bm, const float* __restrict__ bs,
    const __bf16* __restrict__ W1p, const __bf16* __restrict__ W2p,
    const __bf16* __restrict__ WMp, const __bf16* __restrict__ WSp,
    __bf16* __restrict__ h3, __bf16* __restrict__ s_t)
{
    __shared__ __align__(16) char pool[38528];
    const int t = threadIdx.x;
    const int bx = blockIdx.x;
    const int r3 = bx % 3;
    const int g  = bx / 3;

    if (r3 < 2) {
        // ------------------------------------------------ conv path
        const int o = 2 * g + r3;              // 0..4095
        float* wmax = (float*)pool;            // 16 B
        int*   scnt = (int*)(pool + 16);
        const float* row = conn + (size_t)o * 8192;
        float4 v[8];
        float m = -1e30f;
#pragma unroll
        for (int q = 0; q < 8; q++) {
            v[q] = *(const float4*)(row + (size_t)(q * 256 + t) * 4);
            m = fmaxf(m, fmaxf(fmaxf(v[q].x, v[q].y), fmaxf(v[q].z, v[q].w)));
        }
        __syncthreads();   // all reads drained before in-place overwrite
        __bf16* drow = cb + (size_t)o * rowstride;
#pragma unroll
        for (int q = 0; q < 8; q++) {
            bf16x4 w;
            w[0] = (__bf16)v[q].x; w[1] = (__bf16)v[q].y;
            w[2] = (__bf16)v[q].z; w[3] = (__bf16)v[q].w;
            *(bf16x4*)(drow + (size_t)(q * 256 + t) * 4) = w;
        }
#pragma unroll
        for (int off = 32; off > 0; off >>= 1) m = fmaxf(m, __shfl_down(m, off, 64));
        if ((t & 63) == 0) wmax[t >> 6] = m;
        if (t == 0) *scnt = 0;
        __syncthreads();
        const float rmax = fmaxf(fmaxf(wmax[0], wmax[1]), fmaxf(wmax[2], wmax[3]));
#pragma unroll
        for (int q = 0; q < 8; q++) {
            float vv[4] = {v[q].x, v[q].y, v[q].z, v[q].w};
#pragma unroll
            for (int e = 0; e < 4; e++) {
                if (vv[e] >= rmax) {
                    int p = atomicAdd(scnt, 1);
                    if (p < 16) idx[o * 16 + p] = (q * 256 + t) * 4 + e;
                }
            }
        }
        __syncthreads();
        if (t == 0) cnt[o] = *scnt < 16 ? *scnt : 16;
        return;
    }

    // ---------------------------------------------------- chain path
    const int b  = g >> 7;                 // 0..15
    const int p0 = (g & 127) * 64;         // 0..8128
    __bf16* buf0 = (__bf16*)pool;          // 64*136 = 17408 B
    __bf16* un   = (__bf16*)(pool + 17408);// 128*72 = 18432 B
    float*  bl   = (float*)(pool + 35840); // 672 floats = 2688 B
    __bf16* St   = un;                     // 64 x 136 fits in 128*72 (18432)
    __bf16* H1t  = un;                     // 64 x 104
    __bf16* OutT = un;                     // 128 x 72
    float* b1l = bl;       float* p1l = bl + 96;
    float* b2l = bl + 192; float* p2l = bl + 304;
    float* bml = bl + 416; float* bsl = bl + 544;

    const int lane = t & 63, wid = t >> 6;

    for (int i = t; i < 96; i += 256)  { b1l[i] = (i < 83)  ? b1[i] : 0.f; p1l[i] = (i < 83)  ? p1[i] : 0.f; }
    for (int i = t; i < 112; i += 256) { b2l[i] = (i < 102) ? b2[i] : 0.f; p2l[i] = (i < 102) ? p2[i] : 0.f; }
    for (int i = t; i < 128; i += 256) { bml[i] = bm[i]; bsl[i] = bs[i]; }

    {
        // vectorized x staging: float4 along positions, transpose into LDS
        const int pg = (t & 15) * 4;        // position base 0..60
        const int c0 = t >> 4;              // 0..15
#pragma unroll
        for (int it = 0; it < 4; it++) {
            int c = it * 16 + c0;
            float4 xv = *(const float4*)(x + ((size_t)b * 64 + c) * 8192 + p0 + pg);
            buf0[(pg + 0) * 72 + c] = (__bf16)xv.x;
            buf0[(pg + 1) * 72 + c] = (__bf16)xv.y;
            buf0[(pg + 2) * 72 + c] = (__bf16)xv.z;
            buf0[(pg + 3) * 72 + c] = (__bf16)xv.w;
        }
    }
    __syncthreads();

    const int quad4 = (lane >> 4) << 2;
    const int l15 = lane & 15;

    // shortcut S = WS*X + bs  (8 mt x 4 nt) -> St[pos][ch] in LDS
    for (int tt = wid; tt < 32; tt += 4) {
        int mt = tt >> 2, nt = tt & 3;
        f32x4 a = mfma_tile<2>(WSp, 64, mt, buf0, 72, nt, lane);
        int ocb = mt * 16 + quad4;
        int pos = nt * 16 + l15;
        bf16x4 ov;
#pragma unroll
        for (int r = 0; r < 4; r++) ov[r] = (__bf16)(a[r] + bsl[ocb + r]);
        *(bf16x4*)(&St[pos * 136 + ocb]) = ov;
    }
    __syncthreads();

    // coalesced St -> s_t flush: wave writes 4 positions x 256B = 1KB
#pragma unroll
    for (int it = 0; it < 4; it++) {
        int lin = it * 256 + t;            // 0..1023
        int pos = lin >> 4, pc = lin & 15;
        bf16x8 v = *(const bf16x8*)(&St[pos * 136 + pc * 8]);
        *(bf16x8*)(s_t + ((size_t)b * 8192 + p0 + pos) * 128 + pc * 8) = v;
    }
    __syncthreads();

    // H1 = cprelu(W1*X + b1)  (6 mt x 4 nt) -> H1t (reuses un, St dead)
    for (int tt = wid; tt < 24; tt += 4) {
        int mt = tt >> 2, nt = tt & 3;
        f32x4 a = mfma_tile<2>(W1p, 64, mt, buf0, 72, nt, lane);
        int ocb = mt * 16 + quad4;
        int pos = nt * 16 + l15;
        bf16x4 ov;
#pragma unroll
        for (int r = 0; r < 4; r++) {
            float v = a[r] + b1l[ocb + r];
            v = (v >= 0.f) ? v : v * p1l[ocb + r];
            ov[r] = (__bf16)((v - PM) * PIS);
        }
        *(bf16x4*)(&H1t[pos * 104 + ocb]) = ov;
    }
    __syncthreads();

    // H2 = cprelu(W2*H1 + b2)  (7 mt x 4 nt), into buf0 (Xt dead)
    for (int tt = wid; tt < 28; tt += 4) {
        int mt = tt >> 2, nt = tt & 3;
        f32x4 a = mfma_tile<3>(W2p, 96, mt, H1t, 104, nt, lane);
        int ocb = mt * 16 + quad4;
        int pos = nt * 16 + l15;
        bf16x4 ov;
#pragma unroll
        for (int r = 0; r < 4; r++) {
            float v = a[r] + b2l[ocb + r];
            v = (v >= 0.f) ? v : v * p2l[ocb + r];
            ov[r] = (__bf16)((v - PM) * PIS);
        }
        *(bf16x4*)(&buf0[pos * 136 + ocb]) = ov;
    }
    // zero H2 pad channels 112..127
    for (int i = t; i < 64 * 16; i += 256) {
        int pos = i >> 4, c = 112 + (i & 15);
        buf0[pos * 136 + c] = (__bf16)0.f;
    }
    __syncthreads();   // also: H1t reads done before OutT overwrites region

    // H3 = WM*H2 + bm  (8 mt x 4 nt) -> OutT[ch][pos] in LDS
    for (int tt = wid; tt < 32; tt += 4) {
        int mt = tt >> 2, nt = tt & 3;
        f32x4 a = mfma_tile<4>(WMp, 128, mt, buf0, 136, nt, lane);
        int ocb = mt * 16 + quad4;
        int pos = nt * 16 + l15;
#pragma unroll
        for (int r = 0; r < 4; r++)
            OutT[(ocb + r) * 72 + pos] = (__bf16)(a[r] + bml[ocb + r]);
    }
    __syncthreads();

    // coalesced OutT -> h3 (bf16x8 per lane, 128B per channel row)
#pragma unroll
    for (int it = 0; it < 4; it++) {
        int lin = it * 256 + t;       // 0..1023
        int ch = lin >> 3, pc = lin & 7;
        bf16x8 v = *(const bf16x8*)(OutT + ch * 72 + pc * 8);
        *(bf16x8*)(h3 + ((size_t)b * 128 + ch) * 8192 + p0 + pc * 8) = v;
    }
}

// ---------------------------------------------------------------- k_gemm
// out[2048,4096] = combine(A[2048,8192](bf16) x B[4096,bstride](bf16)).
// r3-measured config (178.8 us): 128x128 tile, BK=64, 4 waves, full K,
// fused combine epilogue. Frozen — r5 showed the bottleneck is LDS BW,
// not wave count (occupancy 2x'd with no MfmaUtil gain).
// XOR swizzle: 16B chunk (row, c) of a 64-elem row stored at c ^ (row & 7).
__global__ __launch_bounds__(256, 2) void k_gemm(const __bf16* __restrict__ A,
                                                 const __bf16* __restrict__ B,
                                                 size_t bstride,
                                                 float* __restrict__ out,
                                                 const __bf16* __restrict__ s_t,
                                                 const int* __restrict__ idx,
                                                 const int* __restrict__ cnt,
                                                 const float* __restrict__ p3)
{
    __shared__ __align__(16) char pool[66560];
    __bf16* la = (__bf16*)pool;              // 128*64 bf16 = 16384 B
    __bf16* lb = (__bf16*)(pool + 16384);    // 128*64 bf16 = 16384 B
    float*  sp = (float*)pool;               // [128][129] = 66048 B (after loop)
    float* p3l = (float*)(pool + 66048);     // 512 B

    const int t = threadIdx.x;
    const int lane = t & 63;
    const int wid = t >> 6;
    const int tMi = blockIdx.y;              // batch 0..15
    const int tM = tMi * 128;
    const int tN = blockIdx.x * 128;
    const int wm2 = (wid & 1) * 64;
    const int wn2 = (wid >> 1) * 64;

    f32x4 acc[4][4];
    const f32x4 zero = {0.f, 0.f, 0.f, 0.f};
#pragma unroll
    for (int i = 0; i < 4; i++)
#pragma unroll
        for (int j = 0; j < 4; j++) acc[i][j] = zero;

    // staging: 4 issues per matrix; issue i covers rows i*32..i*32+31
    const int tr = t >> 3;                    // 0..31
    const int sc = (t & 7) ^ (tr & 7);        // swizzled global chunk
    const __bf16* pA[4];
    const __bf16* pB[4];
#pragma unroll
    for (int i = 0; i < 4; i++) {
        pA[i] = A + (size_t)(tM + i * 32 + tr) * 8192 + sc * 8;
        pB[i] = B + (size_t)(tN + i * 32 + tr) * bstride + sc * 8;
    }

    const int l15 = lane & 15;
    const int q = lane >> 4;
    int aoff[4], boff[4];
#pragma unroll
    for (int i = 0; i < 4; i++) {
        int row = wm2 + i * 16 + l15;
        aoff[i] = row * 64 + ((q ^ (row & 7)) * 8);
    }
#pragma unroll
    for (int j = 0; j < 4; j++) {
        int row = wn2 + j * 16 + l15;
        boff[j] = row * 64 + ((q ^ (row & 7)) * 8);
    }

    for (int it = 0; it < 128; it++) {
#pragma unroll
        for (int i = 0; i < 4; i++) load_lds16(pA[i], la + (i * 256 + t) * 8);
#pragma unroll
        for (int i = 0; i < 4; i++) load_lds16(pB[i], lb + (i * 256 + t) * 8);
#pragma unroll
        for (int i = 0; i < 4; i++) { pA[i] += 64; pB[i] += 64; }
        __syncthreads();
#pragma unroll
        for (int ks = 0; ks < 2; ks++) {
            bf16x8 af[4], bfr[4];
#pragma unroll
            for (int i = 0; i < 4; i++) af[i]  = *(const bf16x8*)(la + (aoff[i] ^ (ks << 5)));
#pragma unroll
            for (int j = 0; j < 4; j++) bfr[j] = *(const bf16x8*)(lb + (boff[j] ^ (ks << 5)));
#pragma unroll
            for (int i = 0; i < 4; i++)
#pragma unroll
                for (int j = 0; j < 4; j++)
                    acc[i][j] = __builtin_amdgcn_mfma_f32_16x16x32_bf16(af[i], bfr[j], acc[i][j], 0, 0, 0);
        }
        __syncthreads();
    }
    // loop ends with __syncthreads(): all LDS reads done, LDS-DMA drained ->
    // pool is safe to reuse.

    // ---- shortcut gather: sp[l][c] = sum_{k<cnt[tN+l]} s_t[b, idx_k, c]
    {
        const int l = t >> 1;                 // col-in-tile 0..127
        const int part = t & 1;               // channel half
        const int col = tN + l;
        const int n = cnt[col];
        const __bf16* base = s_t + ((size_t)tMi * 8192) * 128 + part * 64;
        float* spr = sp + l * 129 + part * 64;
        {
            const __bf16* row = base + (size_t)idx[col * 16] * 128;
#pragma unroll
            for (int j = 0; j < 8; j++) {
                bf16x8 v = *(const bf16x8*)(row + j * 8);
#pragma unroll
                for (int u = 0; u < 8; u++) spr[j * 8 + u] = (float)v[u];
            }
        }
        for (int k = 1; k < n; k++) {
            const __bf16* row = base + (size_t)idx[col * 16 + k] * 128;
#pragma unroll
            for (int j = 0; j < 8; j++) {
                bf16x8 v = *(const bf16x8*)(row + j * 8);
#pragma unroll
                for (int u = 0; u < 8; u++) spr[j * 8 + u] += (float)v[u];
            }
        }
        if (t < 128) p3l[t] = p3[t];
    }
    __syncthreads();

    // ---- fused combine epilogue
    const int quad4 = q * 4;
#pragma unroll
    for (int i = 0; i < 4; i++) {
        int gm = tM + wm2 + i * 16 + quad4;
#pragma unroll
        for (int j = 0; j < 4; j++) {
            int gn = tN + wn2 + j * 16 + l15;
            int colT = wn2 + j * 16 + l15;
#pragma unroll
            for (int r = 0; r < 4; r++) {
                int c = wm2 + i * 16 + quad4 + r;      // channel 0..127
                float v = acc[i][j][r];
                float pw = p3l[c];
                float y = (v >= 0.f) ? v : v * pw;
                y = (y - PM) * PIS;
                out[(size_t)(gm + r) * 4096 + gn] = sp[colT * 129 + c] * RHALF + y * RHALF;
            }
        }
    }
}

// ---------------------------------------------------------------- launch
extern "C" void kernel_launch(void* const* d_in, const int* in_sizes, int n_in,
                              void* d_out, int out_size, void* d_ws, size_t ws_size,
                              hipStream_t stream) {
    (void)in_sizes; (void)n_in; (void)out_size;
    const float* x    = (const float*)d_in[0];
    const float* conn = (const float*)d_in[1];
    const float* w1   = (const float*)d_in[2];
    const float* b1   = (const float*)d_in[3];
    const float* p1   = (const float*)d_in[4];
    const float* w2   = (const float*)d_in[5];
    const float* b2   = (const float*)d_in[6];
    const float* p2   = (const float*)d_in[7];
    const float* wm   = (const float*)d_in[8];
    const float* bm   = (const float*)d_in[9];
    const float* p3   = (const float*)d_in[10];
    const float* wsw  = (const float*)d_in[11];
    const float* bs   = (const float*)d_in[12];
    float* out = (float*)d_out;

    char* ws = (char*)d_ws;
    __bf16* h3  = (__bf16*)(ws);                          // 33,554,432 B
    __bf16* s_t = (__bf16*)(ws + 33554432);               // 33,554,432 B
    __bf16* W1p = (__bf16*)(ws + 67108864);               // 12,288
    __bf16* W2p = (__bf16*)(ws + 67108864 + 12288);       // 21,504
    __bf16* WMp = (__bf16*)(ws + 67108864 + 33792);       // 32,768
    __bf16* WSp = (__bf16*)(ws + 67108864 + 66560);       // 16,384
    int* idx = (int*)(ws + 67108864 + 82944);             // 262,144
    int* cnt = (int*)(ws + 67108864 + 82944 + 262144);    // 16,384
    const size_t connb_off = 67108864 + 82944 + 262144 + 16384;   // 67,470,336

    __bf16* connb;
    size_t  cstride;
    if (ws_size >= connb_off + (size_t)4096 * 8192 * 2) {
        connb = (__bf16*)(ws + connb_off);
        cstride = 8192;
    } else {
        connb = (__bf16*)const_cast<float*>(conn);
        cstride = 16384;   // bf16 row packed into first half of its fp32 row
    }

    k_prep<<<32, 256, 0, stream>>>(w1, w2, wm, wsw, W1p, W2p, WMp, WSp);
    k_cc<<<6144, 256, 0, stream>>>(conn, connb, cstride, cnt, idx,
                                   x, b1, p1, b2, p2, bm, bs,
                                   W1p, W2p, WMp, WSp, h3, s_t);
    k_gemm<<<dim3(32, 16), 256, 0, stream>>>(h3, connb, cstride, out, s_t, idx, cnt, p3);
}